// Round 7
// baseline (320.829 us; speedup 1.0000x reference)
//
#include <hip/hip_runtime.h>

// Problem constants (fixed by the reference).
#define BATCH   128
#define RANK    64
#define HIDDEN  4096
#define NADPT   256

// Geometry: 256 threads = 128 float4-columns x 2 rank-halves.
// Each thread accumulates RANK/2=32 ranks for one float4 column; the two
// halves combine through LDS. grid=(128,8)=1024 blocks x 4 waves
// -> 16 waves/CU (2x round-6) and half the dependent-load chain length.
// Probe: distinguishes latency-bound (~drop 10-20us) from HBM-floor (flat).
#define TPB     256
#define COLS    128
#define HCHUNK  (COLS * 4)   // 512
#define RHALF   (RANK / 2)   // 32

// Native clang vector type: __builtin_nontemporal_store rejects
// HIP_vector_type<float,4> but accepts ext_vector_type.
typedef float vfloat4 __attribute__((ext_vector_type(4)));

__global__ __launch_bounds__(TPB) void PaddedLoraB_59459527246474_kernel(
    const float* __restrict__ y,      // [BATCH, RANK] f32 (harness upcasts f16->f32)
    const int*   __restrict__ wids,   // [BATCH]
    const float* __restrict__ loraB,  // [NADPT, RANK, HIDDEN] f32
    float*       __restrict__ out)    // [BATCH, HIDDEN] f32
{
    const int b   = blockIdx.x;
    const int wid = wids[b] & (NADPT - 1);   // clamp: OOB insurance only
    const int col = threadIdx.x & (COLS - 1);   // 0..127: which float4 column
    const int rh  = threadIdx.x >> 7;           // 0/1: which rank half
    const int h0  = blockIdx.y * HCHUNK + col * 4;   // max 4092

    // Stage 2*y[b,:] into LDS (fold the output scale; exact in fp32).
    // Per-iteration reads are wave-uniform -> broadcast, no conflicts.
    __shared__ float   ysh[RANK];
    __shared__ vfloat4 part[COLS];
    if (threadIdx.x < RANK) {
        ysh[threadIdx.x] = 2.0f * y[b * RANK + threadIdx.x];
    }
    __syncthreads();

    const float* Bp = loraB + (size_t)wid * (RANK * HIDDEN)
                            + (size_t)(rh * RHALF) * HIDDEN + h0;

    float acc0 = 0.f, acc1 = 0.f, acc2 = 0.f, acc3 = 0.f;

#pragma unroll 8
    for (int r = 0; r < RHALF; ++r) {
        const float4 v = *(const float4*)(Bp + (size_t)r * HIDDEN);  // 16B/lane coalesced
        const float yv = ysh[rh * RHALF + r];
        acc0 = fmaf(yv, v.x, acc0);
        acc1 = fmaf(yv, v.y, acc1);
        acc2 = fmaf(yv, v.z, acc2);
        acc3 = fmaf(yv, v.w, acc3);
    }

    // Combine the two rank-halves through LDS; rh==0 threads store.
    if (rh == 1) {
        vfloat4 p; p.x = acc0; p.y = acc1; p.z = acc2; p.w = acc3;
        part[col] = p;
    }
    __syncthreads();
    if (rh == 0) {
        const vfloat4 p = part[col];
        vfloat4 o;
        o.x = acc0 + p.x; o.y = acc1 + p.y; o.z = acc2 + p.z; o.w = acc3 + p.w;
        __builtin_nontemporal_store(o, (vfloat4*)(out + (size_t)b * HIDDEN + h0));
    }
}

extern "C" void kernel_launch(void* const* d_in, const int* in_sizes, int n_in,
                              void* d_out, int out_size, void* d_ws, size_t ws_size,
                              hipStream_t stream) {
    // Bind inputs by element count (distinct sizes): y=8192, wids=128,
    // lora_B=67108864. Reference f16 tensors arrive as f32 (harness decode
    // paths are bf16/f32/int32 only; bf16-bits interpretation gave 2.2e19).
    const float* y     = nullptr;
    const int*   wids  = nullptr;
    const float* loraB = nullptr;
    for (int i = 0; i < n_in; ++i) {
        if (in_sizes[i] == BATCH * RANK)               y     = (const float*)d_in[i];
        else if (in_sizes[i] == BATCH)                 wids  = (const int*)d_in[i];
        else if (in_sizes[i] == NADPT * RANK * HIDDEN) loraB = (const float*)d_in[i];
    }
    float* out = (float*)d_out;  // [128,1,4096] f32

    dim3 grid(BATCH, HIDDEN / HCHUNK, 1);  // (128, 8) = 1024 blocks
    dim3 block(TPB, 1, 1);
    PaddedLoraB_59459527246474_kernel<<<grid, block, 0, stream>>>(y, wids, loraB, out);
}